// Round 1
// baseline (48.907 us; speedup 1.0000x reference)
//
#include <hip/hip_runtime.h>
#include <hip/hip_bf16.h>
#include <cstdint>

// B=2048, C=256, P=15 (pad to 16), channels=512, groups=4 (128 ch each)
#define NB_B 2048
#define NTOT (2048 * 16)   // 32768 padded cols (n = b*16 + p)
#define NVALID (2048 * 15) // 30720
#define EPS_ 1e-5f

typedef __bf16 bf16x8 __attribute__((ext_vector_type(8)));
typedef float f32x16 __attribute__((ext_vector_type(16)));
typedef unsigned short u16x8 __attribute__((ext_vector_type(8)));

__device__ __forceinline__ unsigned short f2bf(float f) {
  unsigned u = __float_as_uint(f);
  u += 0x7FFFu + ((u >> 16) & 1u);   // RNE
  return (unsigned short)(u >> 16);
}
__device__ __forceinline__ float bf2f(unsigned short h) {
  return __uint_as_float((unsigned)h << 16);
}

// ---- prologue: conv_w f32 [4][128][128] -> bf16 in MFMA A-fragment order ----
// Wf[g][mt][ks][lane][j] = w[g][o=mt*32+(lane&31)][i=ks*16+(lane>>5)*8+j]
__global__ void k_wprep(const float* __restrict__ w, unsigned short* __restrict__ wf) {
  int q = blockIdx.x * 256 + threadIdx.x;  // 0..8191
  int l = q & 63, ks = (q >> 6) & 7, mt = (q >> 9) & 3, g = q >> 11;
  int o = mt * 32 + (l & 31);
  int i = ks * 16 + (l >> 5) * 8;
  const float* src = w + ((size_t)(g * 128 + o) * 128 + i);
  u16x8 v;
#pragma unroll
  for (int j = 0; j < 8; ++j) v[j] = f2bf(src[j]);
  *(u16x8*)(wf + (size_t)q * 8) = v;
}

// ---- main GEMM: build Y (xs | tmp) per 4 batches, grouped conv via MFMA ----
// Z[ch][n] (bf16, raw W*y, no bias) ; n = b*16+p, pad col p=15 stores exact 0
__global__ __launch_bounds__(256, 2) void k_gemm(const float* __restrict__ x,
                                                 const unsigned short* __restrict__ wf,
                                                 unsigned short* __restrict__ Z) {
  __shared__ unsigned short Yt[64 * 520];  // [col 0..63][ch 0..511], stride 520 (=65*16B rows)
  __shared__ float xs[3840];               // one b-slab f32
  const int t = threadIdx.x;
  const int b0 = blockIdx.x * 4;

  for (int bi = 0; bi < 4; ++bi) {
    const float* xb = x + (size_t)(b0 + bi) * (256 * 15);
#pragma unroll
    for (int k = 0; k < 15; ++k) xs[k * 256 + t] = xb[k * 256 + t];
    __syncthreads();
    // thread t = channel c
    float v[15];
#pragma unroll
    for (int p = 0; p < 15; ++p) v[p] = xs[t * 15 + p];
    float pm[5];
#pragma unroll
    for (int q = 0; q < 5; ++q) pm[q] = fmaxf(fmaxf(v[3 * q], v[3 * q + 1]), v[3 * q + 2]);
    float mq[5];
    mq[0] = fmaxf(fmaxf(pm[1], pm[2]), fmaxf(pm[3], pm[4]));
    mq[1] = fmaxf(fmaxf(pm[0], pm[2]), fmaxf(pm[3], pm[4]));
    mq[2] = fmaxf(fmaxf(pm[0], pm[1]), fmaxf(pm[3], pm[4]));
    mq[3] = fmaxf(fmaxf(pm[0], pm[1]), fmaxf(pm[2], pm[4]));
    mq[4] = fmaxf(fmaxf(pm[0], pm[1]), fmaxf(pm[2], pm[3]));
    const int c0 = bi * 16;
#pragma unroll
    for (int p = 0; p < 15; ++p) {
      Yt[(c0 + p) * 520 + t] = f2bf(v[p]);                     // xs -> ch 0..255
      Yt[(c0 + p) * 520 + 256 + t] = f2bf(mq[p / 3] - v[p]);   // tmp -> ch 256..511
    }
    Yt[(c0 + 15) * 520 + t] = 0;        // pad col
    Yt[(c0 + 15) * 520 + 256 + t] = 0;
    __syncthreads();
  }

  // MFMA phase: wave g handles group g (128 out ch = 4 mtiles of 32)
  const int lane = t & 63, g = t >> 6;
  const int l31 = lane & 31, lh = lane >> 5;
  const bf16x8* Wfv = (const bf16x8*)wf;
  const int gn0 = blockIdx.x * 64;

  for (int mp = 0; mp < 2; ++mp) {  // pair of mtiles
    bf16x8 wr[2][8];
#pragma unroll
    for (int mm = 0; mm < 2; ++mm)
#pragma unroll
      for (int ks = 0; ks < 8; ++ks)
        wr[mm][ks] = Wfv[(size_t)(((g * 4 + mp * 2 + mm) * 8 + ks) * 64 + lane)];
#pragma unroll
    for (int nt = 0; nt < 2; ++nt) {
      const int col = nt * 32 + l31;
      const unsigned short* yrow = &Yt[col * 520 + g * 128 + lh * 8];
      bf16x8 bfr[8];
#pragma unroll
      for (int ks = 0; ks < 8; ++ks)
        bfr[ks] = *(const bf16x8*)(yrow + ks * 16);
      f32x16 a0, a1;
#pragma unroll
      for (int r = 0; r < 16; ++r) { a0[r] = 0.f; a1[r] = 0.f; }
#pragma unroll
      for (int ks = 0; ks < 8; ++ks) {
        a0 = __builtin_amdgcn_mfma_f32_32x32x16_bf16(wr[0][ks], bfr[ks], a0, 0, 0, 0);
        a1 = __builtin_amdgcn_mfma_f32_32x32x16_bf16(wr[1][ks], bfr[ks], a1, 0, 0, 0);
      }
      const int n = gn0 + col;
      unsigned short* zc = Z + n;
#pragma unroll
      for (int r = 0; r < 16; ++r) {
        int row = (r & 3) + 8 * (r >> 2) + 4 * lh;   // C/D: col=lane&31, this row formula (m74/m101)
        size_t ch0 = (size_t)(g * 128 + mp * 64 + row);
        zc[ch0 * NTOT] = f2bf(a0[r]);
        zc[(ch0 + 32) * NTOT] = f2bf(a1[r]);
      }
    }
  }
}

// ---- per-channel stats -> folded (a, b): out = relu(z*a + b) ----
__global__ void k_stats(const unsigned short* __restrict__ Z,
                        const float* __restrict__ gamma, const float* __restrict__ beta,
                        float2* __restrict__ AB) {
  const int ch = blockIdx.x, t = threadIdx.x;
  const u16x8* zr = (const u16x8*)(Z + (size_t)ch * NTOT);
  float s = 0.f, s2 = 0.f;
#pragma unroll 4
  for (int it = 0; it < 16; ++it) {
    u16x8 u = zr[it * 256 + t];
#pragma unroll
    for (int j = 0; j < 8; ++j) { float f = bf2f(u[j]); s += f; s2 += f * f; }
  }
#pragma unroll
  for (int m = 32; m >= 1; m >>= 1) { s += __shfl_xor(s, m, 64); s2 += __shfl_xor(s2, m, 64); }
  __shared__ float ls[4], ls2[4];
  if ((t & 63) == 0) { ls[t >> 6] = s; ls2[t >> 6] = s2; }
  __syncthreads();
  if (t == 0) {
    float S = ls[0] + ls[1] + ls[2] + ls[3];
    float S2 = ls2[0] + ls2[1] + ls2[2] + ls2[3];
    const float inv = 1.f / (float)NVALID;   // pad cols contribute exact 0 to both sums
    float mean = S * inv;
    float var = fmaxf(S2 * inv - mean * mean, 0.f);
    float a = gamma[ch] * rsqrtf(var + EPS_);
    AB[ch] = make_float2(a, beta[ch] - mean * a);
  }
}

// ---- finalize: transpose [ch][n] -> [b][ch][p], fused affine + relu ----
__global__ __launch_bounds__(256, 2) void k_final(const unsigned short* __restrict__ Z,
                                                  const float2* __restrict__ AB,
                                                  float* __restrict__ out) {
  __shared__ unsigned short zt[512 * 72];  // [ch][64 cols] padded to 72 (144B rows)
  __shared__ float aArr[512], bArr[512];
  const int t = threadIdx.x;
  const int b0 = blockIdx.x * 4, n0 = b0 * 16;
#pragma unroll
  for (int i = 0; i < 2; ++i) {
    int ch = i * 256 + t;
    float2 ab = AB[ch];
    aArr[ch] = ab.x; bArr[ch] = ab.y;
  }
#pragma unroll 4
  for (int it = 0; it < 16; ++it) {
    int q = it * 256 + t;             // 4096 chunks of 16B
    int ch = q >> 3, o8 = (q & 7) * 8;
    *(u16x8*)&zt[ch * 72 + o8] = *(const u16x8*)(Z + (size_t)ch * NTOT + n0 + o8);
  }
  __syncthreads();
  for (int bi = 0; bi < 4; ++bi) {
    float* slab = out + (size_t)(b0 + bi) * 7680;
#pragma unroll 5
    for (int k = 0; k < 30; ++k) {
      int e = k * 256 + t;
      int ch = e / 15, p = e - ch * 15;
      float val = bf2f(zt[ch * 72 + bi * 16 + p]);
      slab[e] = fmaxf(fmaf(val, aArr[ch], bArr[ch]), 0.f);
    }
  }
}

extern "C" void kernel_launch(void* const* d_in, const int* in_sizes, int n_in,
                              void* d_out, int out_size, void* d_ws, size_t ws_size,
                              hipStream_t stream) {
  const float* x = (const float*)d_in[0];
  const float* cw = (const float*)d_in[1];
  // d_in[2] = conv_b: provably cancelled by training-mode BN -> unused
  const float* gamma = (const float*)d_in[3];
  const float* beta = (const float*)d_in[4];

  unsigned short* wf = (unsigned short*)d_ws;            // 65536 bf16 = 128 KB
  unsigned short* Z = wf + 65536;                        // 512*32768 bf16 = 32 MB
  float2* AB = (float2*)(Z + (size_t)512 * NTOT);        // 512 float2 = 4 KB

  hipLaunchKernelGGL(k_wprep, dim3(32), dim3(256), 0, stream, cw, wf);
  hipLaunchKernelGGL(k_gemm, dim3(512), dim3(256), 0, stream, x, wf, Z);
  hipLaunchKernelGGL(k_stats, dim3(512), dim3(256), 0, stream, Z, gamma, beta, AB);
  hipLaunchKernelGGL(k_final, dim3(512), dim3(256), 0, stream, Z, AB, (float*)d_out);
}